// Round 11
// baseline (272.721 us; speedup 1.0000x reference)
//
#include <hip/hip_runtime.h>
#include <math.h>

typedef unsigned short u16;
typedef unsigned int   u32;
using bf16x8 = __attribute__((ext_vector_type(8))) short;
using f32x4  = __attribute__((ext_vector_type(4))) float;
using f32x16 = __attribute__((ext_vector_type(16))) float;

static constexpr int Bb = 2, Tt = 2048, Cc = 1024, Hh = 16, Dd = 64;
static constexpr int QS = 3072;   // fused qkv row stride (u16 elements)
static constexpr float QSCALE = 0.125f * 1.44269504089f;  // folded into Q at QKV epilogue

__device__ __forceinline__ u16 f2bf(float f){
  u32 u = __builtin_bit_cast(u32, f);
  u += 0x7fffu + ((u >> 16) & 1u);
  return (u16)(u >> 16);
}
__device__ __forceinline__ float bf2f(u16 v){
  u32 u = (u32)v << 16;
  return __builtin_bit_cast(float, u);
}

__device__ __forceinline__ void gl2lds16(const void* g, void* l){
  __builtin_amdgcn_global_load_lds((const __attribute__((address_space(1))) void*)g,
                                   (__attribute__((address_space(3))) void*)l, 16, 0, 0);
}

template<int N> __device__ __forceinline__ void waitvm(){
  if constexpr (N == 0) asm volatile("s_waitcnt vmcnt(0)" ::: "memory");
  else if constexpr (N == 3) asm volatile("s_waitcnt vmcnt(3)" ::: "memory");
  else if constexpr (N == 4) asm volatile("s_waitcnt vmcnt(4)" ::: "memory");
  else if constexpr (N == 6) asm volatile("s_waitcnt vmcnt(6)" ::: "memory");
  else if constexpr (N == 8) asm volatile("s_waitcnt vmcnt(8)" ::: "memory");
}

__device__ __forceinline__ void barrier_pin(){
  __builtin_amdgcn_s_barrier();
  __builtin_amdgcn_sched_barrier(0);
}

__device__ __forceinline__ f32x4 mfma16(bf16x8 a, bf16x8 b, f32x4 c){
  return __builtin_amdgcn_mfma_f32_16x16x32_bf16(a, b, c, 0, 0, 0);
}
__device__ __forceinline__ f32x16 mfma32(bf16x8 a, bf16x8 b, f32x16 c){
  return __builtin_amdgcn_mfma_f32_32x32x16_bf16(a, b, c, 0, 0, 0);
}

__device__ __forceinline__ float exp2f_fast(float x){
#if __has_builtin(__builtin_amdgcn_exp2f)
  return __builtin_amdgcn_exp2f(x);
#else
  return __expf(x * 0.69314718056f);
#endif
}

__device__ __forceinline__ float gelu_f(float x){
  return 0.5f * x * (1.0f + erff(x * 0.70710678118654752f));
}

// swap lanes[32:63] of a with lanes[0:31] of b (both results useful)
__device__ __forceinline__ void plane_swap(u32& a, u32& b){
  asm("v_permlane32_swap_b32 %0, %1" : "+v"(a), "+v"(b));
}
__device__ __forceinline__ u32 cvtpk_bf16(float lo, float hi){
  u32 r;
  asm("v_cvt_pk_bf16_f32 %0, %1, %2" : "=v"(r) : "v"(lo), "v"(hi));
  return r;
}

// ---------------- LayerNorm: fp32 row -> bf16 row ----------------
__global__ __launch_bounds__(256) void ln_kernel(const float* __restrict__ x,
    const float* __restrict__ g, const float* __restrict__ b, u16* __restrict__ out)
{
  int row = blockIdx.x;
  int tid = threadIdx.x;
  const float4* xr = (const float4*)(x + (size_t)row * Cc);
  float4 v = xr[tid];
  float s  = v.x + v.y + v.z + v.w;
  float s2 = v.x*v.x + v.y*v.y + v.z*v.z + v.w*v.w;
  #pragma unroll
  for (int off = 1; off < 64; off <<= 1){ s += __shfl_xor(s, off); s2 += __shfl_xor(s2, off); }
  __shared__ float red[8];
  int wid = tid >> 6;
  if ((tid & 63) == 0){ red[wid] = s; red[4 + wid] = s2; }
  __syncthreads();
  s  = red[0] + red[1] + red[2] + red[3];
  s2 = red[4] + red[5] + red[6] + red[7];
  float mu   = s * (1.0f / Cc);
  float var  = s2 * (1.0f / Cc) - mu * mu;
  float rstd = rsqrtf(var + 1e-5f);
  const float4 gg = ((const float4*)g)[tid];
  const float4 bb = ((const float4*)b)[tid];
  ushort4 o;
  o.x = f2bf((v.x - mu) * rstd * gg.x + bb.x);
  o.y = f2bf((v.y - mu) * rstd * gg.y + bb.y);
  o.z = f2bf((v.z - mu) * rstd * gg.z + bb.z);
  o.w = f2bf((v.w - mu) * rstd * gg.w + bb.w);
  *(ushort4*)(out + (size_t)row * Cc + tid * 4) = o;
}

// ---------------- transpose + cast: W[K][N] fp32 -> WT[N][K] bf16 ----------------
__global__ __launch_bounds__(256) void transpose_cast_kernel(const float* __restrict__ in,
    u16* __restrict__ out, int R, int Ccols)
{
  __shared__ float tile[32][33];
  int tx = threadIdx.x, ty = threadIdx.y;
  int c0 = blockIdx.x * 32, r0 = blockIdx.y * 32;
  #pragma unroll
  for (int j = 0; j < 4; j++) tile[ty + j*8][tx] = in[(size_t)(r0 + ty + j*8) * Ccols + c0 + tx];
  __syncthreads();
  #pragma unroll
  for (int j = 0; j < 4; j++) out[(size_t)(c0 + ty + j*8) * R + r0 + tx] = f2bf(tile[tx][ty + j*8]);
}

// ---------------- 4x fused 1024x1024 transpose+cast ----------------
__global__ __launch_bounds__(256) void transpose4_kernel(
    const float* __restrict__ s0, const float* __restrict__ s1,
    const float* __restrict__ s2, const float* __restrict__ s3,
    u16* __restrict__ d0, u16* __restrict__ d1, u16* __restrict__ d2, u16* __restrict__ d3)
{
  __shared__ float tile[32][33];
  int z = blockIdx.z;
  const float* in = (z == 0) ? s0 : (z == 1) ? s1 : (z == 2) ? s2 : s3;
  u16* out        = (z == 0) ? d0 : (z == 1) ? d1 : (z == 2) ? d2 : d3;
  int tx = threadIdx.x, ty = threadIdx.y;
  int c0 = blockIdx.x * 32, r0 = blockIdx.y * 32;
  #pragma unroll
  for (int j = 0; j < 4; j++) tile[ty + j*8][tx] = in[(size_t)(r0 + ty + j*8) * 1024 + c0 + tx];
  __syncthreads();
  #pragma unroll
  for (int j = 0; j < 4; j++) out[(size_t)(c0 + ty + j*8) * 1024 + r0 + tx] = f2bf(tile[tx][ty + j*8]);
}

// ---------------- pack 3 bias vectors into one [3072] ----------------
__global__ __launch_bounds__(256) void pack3_kernel(const float* __restrict__ a,
    const float* __restrict__ b, const float* __restrict__ c, float* __restrict__ o)
{
  int i = blockIdx.x * 256 + threadIdx.x;
  float v = (i < 1024) ? a[i] : (i < 2048 ? b[i - 1024] : c[i - 2048]);
  o[i] = v;
}

// ---------------- v slice of qkv (stride QS) -> vt (B,H,D,T) bf16 ----------------
__global__ __launch_bounds__(256) void transpose_v_kernel(const u16* __restrict__ v, u16* __restrict__ vt)
{
  __shared__ u16 tile[32][33];
  int tx = threadIdx.x, ty = threadIdx.y;
  int bh = blockIdx.z; int b = bh >> 4, h = bh & 15;
  int t0 = blockIdx.x * 32, d0 = blockIdx.y * 32;
  const u16* src = v + (size_t)b * Tt * QS + h * Dd;
  #pragma unroll
  for (int j = 0; j < 4; j++) tile[ty + j*8][tx] = src[(size_t)(t0 + ty + j*8) * QS + d0 + tx];
  __syncthreads();
  u16* dst = vt + (size_t)bh * Dd * Tt;
  #pragma unroll
  for (int j = 0; j < 4; j++) dst[(size_t)(d0 + ty + j*8) * Tt + t0 + tx] = tile[tx][ty + j*8];
}

// ---------------- counted-vmcnt GEMM, BK=32, occupancy-tuned (T4 + T2 + T1) ----------
// LDS per buffer: (BM+BN)*32*2B. 128x128 -> 32KB dbuf -> 3-4 blocks/CU resident.
// Counted vmcnt(NLOADS): next tile's loads stay in flight across both barriers.
// Swizzle (both sides): chunk' = chunk ^ (row&3) ^ ((row>>2)&3).
// EPI 1: f32 (+bias+residual); 2: bf16 (+bias, gelu); 3: bf16 (+bias, q-cols * QSCALE)
template<int BM, int BN, int WM, int WN, int WPEU, int EPI>
__global__ __launch_bounds__(WM * WN * 64, WPEU) void gemmc_kernel(
    const u16* __restrict__ A, const u16* __restrict__ BT,
    const float* __restrict__ bias, const float* __restrict__ resid,
    void* __restrict__ out, int K, int ldA, int ldOut)
{
  constexpr int THREADS = WM * WN * 64;
  constexpr int MF = (BM / WM) / 16;
  constexpr int NF = (BN / WN) / 16;
  constexpr int AG = (BM * 4) / THREADS;   // A gl2lds per thread per K-tile (BK=32)
  constexpr int BG = (BN * 4) / THREADS;
  constexpr int NLOADS = AG + BG;

  __shared__ alignas(16) u16 As[2][BM * 32];
  __shared__ alignas(16) u16 Bs[2][BN * 32];

  const int tid  = threadIdx.x;
  const int lane = tid & 63, wid = tid >> 6;
  const int l15  = lane & 15, lg = lane >> 4;

  // bijective XCD-chunked grid swizzle (all launches have nwg % 8 == 0)
  const int gx  = gridDim.x;
  const int lin = blockIdx.x + gx * blockIdx.y;
  const int nwg = gx * gridDim.y;
  const int wl  = (lin & 7) * (nwg >> 3) + (lin >> 3);
  const int rowBase = (wl % gx) * BM, colBase = (wl / gx) * BN;

  const int wr = wid / WN, wc = wid % WN;

  f32x4 acc[MF][NF] = {};

  auto stage = [&](int buf, int k0){
    #pragma unroll
    for (int j = 0; j < AG; j++){
      int g = tid + THREADS * j;
      int row = g >> 2, p = g & 3;
      int w = p ^ (row & 3) ^ ((row >> 2) & 3);
      gl2lds16(A + (size_t)(rowBase + row) * ldA + k0 + w * 8, (u16*)As[buf] + g * 8);
    }
    #pragma unroll
    for (int j = 0; j < BG; j++){
      int g = tid + THREADS * j;
      int row = g >> 2, p = g & 3;
      int w = p ^ (row & 3) ^ ((row >> 2) & 3);
      gl2lds16(BT + (size_t)(colBase + row) * K + k0 + w * 8, (u16*)Bs[buf] + g * 8);
    }
  };

  stage(0, 0);
  const int nt = K >> 5;
  int cur = 0;
  for (int t = 0; t < nt; ++t, cur ^= 1){
    if (t + 1 < nt){ stage(cur ^ 1, (t + 1) << 5); waitvm<NLOADS>(); }
    else           { waitvm<0>(); }
    __builtin_amdgcn_s_barrier();
    __builtin_amdgcn_sched_barrier(0);

    const u16* Asb = (const u16*)As[cur];
    const u16* Bsb = (const u16*)Bs[cur];

    bf16x8 bfr[NF], afr[MF];
    #pragma unroll
    for (int ni = 0; ni < NF; ni++){
      int r = wc * (BN / WN) + ni * 16 + l15;
      bfr[ni] = *(const bf16x8*)(Bsb + r * 32 + ((lg ^ (r & 3) ^ ((r >> 2) & 3)) << 3));
    }
    #pragma unroll
    for (int mi = 0; mi < MF; mi++){
      int r = wr * (BM / WM) + mi * 16 + l15;
      afr[mi] = *(const bf16x8*)(Asb + r * 32 + ((lg ^ (r & 3) ^ ((r >> 2) & 3)) << 3));
    }
    __builtin_amdgcn_s_setprio(1);
    #pragma unroll
    for (int mi = 0; mi < MF; mi++)
      #pragma unroll
      for (int ni = 0; ni < NF; ni++)
        acc[mi][ni] = mfma16(afr[mi], bfr[ni], acc[mi][ni]);
    __builtin_amdgcn_s_setprio(0);

    __builtin_amdgcn_sched_barrier(0);
    __builtin_amdgcn_s_barrier();
  }

  #pragma unroll
  for (int mi = 0; mi < MF; mi++){
    #pragma unroll
    for (int ni = 0; ni < NF; ni++){
      int row = rowBase + wr * (BM / WM) + mi * 16 + lg * 4;
      int col = colBase + wc * (BN / WN) + ni * 16 + l15;
      float bc = bias[col];
      #pragma unroll
      for (int r = 0; r < 4; r++){
        float val = acc[mi][ni][r] + bc;
        size_t idx = (size_t)(row + r) * ldOut + col;
        if constexpr (EPI == 1)      ((float*)out)[idx] = val + resid[idx];
        else if constexpr (EPI == 2) ((u16*)out)[idx]   = f2bf(gelu_f(val));
        else if constexpr (EPI == 3) ((u16*)out)[idx]   = f2bf(col < 1024 ? val * QSCALE : val);
        else                         ((u16*)out)[idx]   = f2bf(val);
      }
    }
  }
}

// ---------------- Flash attention, swapped 32x32, KV-split x2 ----------------
// Q pre-scaled by QSCALE (scores arrive in exp2 domain). Each split writes
// per-split NORMALIZED O (bf16) + (m, lsum); combine does the convex combination.
__global__ __launch_bounds__(256, 4) void attn_kernel(const u16* __restrict__ q, const u16* __restrict__ k,
    const u16* __restrict__ vt, u16* __restrict__ opart, float* __restrict__ ml)
{
  __shared__ alignas(16) u16 Ks[2][64 * 64];
  __shared__ alignas(16) u16 Vs[2][64 * 64];
  int tid  = threadIdx.x;
  int lane = tid & 63, wid = tid >> 6;
  int l31  = lane & 31, hi = lane >> 5;

  int lin = blockIdx.x + 16 * blockIdx.y;
  int wl  = (lin & 7) * 64 + (lin >> 3);
  int qt  = wl & 15, bh = wl >> 4;
  int b = bh >> 4, h = bh & 15;
  int split = blockIdx.z;
  int kt0 = split * (Tt / 2);

  int qglob = qt * 128 + wid * 32 + l31;

  const u16* qp = q + ((size_t)b * Tt + qglob) * QS + h * Dd + hi * 8;
  bf16x8 qf[4];
  #pragma unroll
  for (int s = 0; s < 4; s++) qf[s] = *(const bf16x8*)(qp + s * 16);

  const u16* kbase = k  + (size_t)b * Tt * QS + h * Dd;
  const u16* vbase = vt + (size_t)bh * Dd * Tt;

  f32x16 yacc[2] = {};
  float m2 = -1e30f, lsum = 0.f;

  int g0 = tid, g1 = tid + 256;
  int r0 = g0 >> 3, cb0 = (g0 & 7) ^ (r0 & 7);
  int r1 = g1 >> 3, cb1 = (g1 & 7) ^ (r1 & 7);

  auto stageKV = [&](int buf, int kt){
    gl2lds16(kbase + (size_t)(kt + r0) * QS + cb0 * 8, (u16*)Ks[buf] + wid * 512);
    gl2lds16(kbase + (size_t)(kt + r1) * QS + cb1 * 8, (u16*)Ks[buf] + 2048 + wid * 512);
    gl2lds16(vbase + (size_t)r0 * Tt + kt + cb0 * 8,   (u16*)Vs[buf] + wid * 512);
    gl2lds16(vbase + (size_t)r1 * Tt + kt + cb1 * 8,   (u16*)Vs[buf] + 2048 + wid * 512);
  };

  stageKV(0, kt0);
  int cur = 0;
  for (int kt = kt0; kt < kt0 + Tt / 2; kt += 64) {
    if (kt + 64 < kt0 + Tt / 2) { stageKV(cur ^ 1, kt + 64); waitvm<4>(); }
    else                        { waitvm<0>(); }
    barrier_pin();

    const u16* Ksb = (const u16*)Ks[cur];
    const u16* Vsb = (const u16*)Vs[cur];
    int rx = l31 & 7;

    f32x16 st[2] = {};
    __builtin_amdgcn_s_setprio(1);
    #pragma unroll
    for (int nb = 0; nb < 2; nb++){
      const u16* krow = Ksb + (nb * 32 + l31) * 64;
      #pragma unroll
      for (int s = 0; s < 4; s++){
        bf16x8 kf = *(const bf16x8*)(krow + (((s * 2 + hi) ^ rx) << 3));
        st[nb] = mfma32(kf, qf[s], st[nb]);
      }
    }
    __builtin_amdgcn_s_setprio(0);

    float tm[16];
    #pragma unroll
    for (int i = 0; i < 16; i++) tm[i] = fmaxf(st[0][i], st[1][i]);
    #pragma unroll
    for (int w = 8; w; w >>= 1)
      #pragma unroll
      for (int i = 0; i < w; i++) tm[i] = fmaxf(tm[i], tm[i + w]);
    u32 ma = __builtin_bit_cast(u32, tm[0]), mb = ma;
    plane_swap(ma, mb);
    float mx = fmaxf(__builtin_bit_cast(float, ma), __builtin_bit_cast(float, mb));

    float mnew = fmaxf(m2, mx);
    float alpha = exp2f_fast(m2 - mnew);
    m2 = mnew;

    #pragma unroll
    for (int nb = 0; nb < 2; nb++)
      #pragma unroll
      for (int i = 0; i < 16; i++)
        st[nb][i] = exp2f_fast(st[nb][i] - m2);

    float ts[16];
    #pragma unroll
    for (int i = 0; i < 16; i++) ts[i] = st[0][i] + st[1][i];
    #pragma unroll
    for (int w = 8; w; w >>= 1)
      #pragma unroll
      for (int i = 0; i < w; i++) ts[i] += ts[i + w];
    u32 sa = __builtin_bit_cast(u32, ts[0]), sb = sa;
    plane_swap(sa, sb);
    lsum = lsum * alpha + __builtin_bit_cast(float, sa) + __builtin_bit_cast(float, sb);

    #pragma unroll
    for (int nd = 0; nd < 2; nd++)
      #pragma unroll
      for (int i = 0; i < 16; i++) yacc[nd][i] *= alpha;

    bf16x8 pb[4];
    #pragma unroll
    for (int nb = 0; nb < 2; nb++){
      u32 c[8];
      #pragma unroll
      for (int i = 0; i < 8; i++) c[i] = cvtpk_bf16(st[nb][2 * i], st[nb][2 * i + 1]);
      plane_swap(c[0], c[2]); plane_swap(c[1], c[3]);
      plane_swap(c[4], c[6]); plane_swap(c[5], c[7]);
      u32 f0[4] = {c[0], c[1], c[2], c[3]};
      u32 f1[4] = {c[4], c[5], c[6], c[7]};
      pb[nb * 2 + 0] = *(bf16x8*)f0;
      pb[nb * 2 + 1] = *(bf16x8*)f1;
    }

    __builtin_amdgcn_s_setprio(1);
    #pragma unroll
    for (int nd = 0; nd < 2; nd++){
      const u16* vrow = Vsb + (nd * 32 + l31) * 64;
      #pragma unroll
      for (int ks = 0; ks < 4; ks++){
        bf16x8 vf = *(const bf16x8*)(vrow + (((ks * 2 + hi) ^ rx) << 3));
        yacc[nd] = mfma32(vf, pb[ks], yacc[nd]);
      }
    }
    __builtin_amdgcn_s_setprio(0);

    __builtin_amdgcn_sched_barrier(0);
    barrier_pin();
    cur ^= 1;
  }

  float inv = 1.0f / lsum;
  u16* op = opart + ((size_t)split * (Bb * Tt) + (size_t)b * Tt + qglob) * Cc + h * Dd;
  #pragma unroll
  for (int nd = 0; nd < 2; nd++){
    #pragma unroll
    for (int g = 0; g < 4; g++){
      ushort4 o;
      o.x = f2bf(yacc[nd][g * 4 + 0] * inv);
      o.y = f2bf(yacc[nd][g * 4 + 1] * inv);
      o.z = f2bf(yacc[nd][g * 4 + 2] * inv);
      o.w = f2bf(yacc[nd][g * 4 + 3] * inv);
      *(ushort4*)(op + nd * 32 + g * 8 + hi * 4) = o;
    }
  }
  if (hi == 0){
    float* mlp = ml + (((size_t)split * (Bb * Tt) + (size_t)b * Tt + qglob) * Hh + h) * 2;
    mlp[0] = m2; mlp[1] = lsum;
  }
}

// ---------------- combine 2 KV-splits (convex combination of normalized partials) ----
__global__ __launch_bounds__(256) void combine_kernel(const u16* __restrict__ opart,
    const float* __restrict__ ml, u16* __restrict__ y)
{
  int row = blockIdx.x;
  int d0  = threadIdx.x * 4;
  int h   = d0 >> 6;
  const float* p0 = ml + ((size_t)row * Hh + h) * 2;
  const float* p1 = ml + (((size_t)(Bb * Tt) + row) * Hh + h) * 2;
  float m0 = p0[0], l0 = p0[1], m1 = p1[0], l1 = p1[1];
  float M  = fmaxf(m0, m1);
  float u0 = l0 * exp2f_fast(m0 - M), u1 = l1 * exp2f_fast(m1 - M);
  float inv = 1.0f / (u0 + u1);
  float w0 = u0 * inv, w1 = u1 * inv;
  ushort4 a = *(const ushort4*)(opart + (size_t)row * Cc + d0);
  ushort4 c = *(const ushort4*)(opart + ((size_t)(Bb * Tt) + row) * Cc + d0);
  ushort4 o;
  o.x = f2bf(bf2f(a.x) * w0 + bf2f(c.x) * w1);
  o.y = f2bf(bf2f(a.y) * w0 + bf2f(c.y) * w1);
  o.z = f2bf(bf2f(a.z) * w0 + bf2f(c.z) * w1);
  o.w = f2bf(bf2f(a.w) * w0 + bf2f(c.w) * w1);
  *(ushort4*)(y + (size_t)row * Cc + d0) = o;
}

extern "C" void kernel_launch(void* const* d_in, const int* in_sizes, int n_in,
                              void* d_out, int out_size, void* d_ws, size_t ws_size,
                              hipStream_t stream)
{
  (void)in_sizes; (void)n_in; (void)out_size; (void)ws_size;
  const float* x    = (const float*)d_in[0];
  const float* Wq   = (const float*)d_in[1];
  const float* bq   = (const float*)d_in[2];
  const float* Wk   = (const float*)d_in[3];
  const float* bk   = (const float*)d_in[4];
  const float* Wv   = (const float*)d_in[5];
  const float* bv   = (const float*)d_in[6];
  const float* Wo   = (const float*)d_in[7];
  const float* bo   = (const float*)d_in[8];
  const float* ln1g = (const float*)d_in[9];
  const float* ln1b = (const float*)d_in[10];
  const float* ln2g = (const float*)d_in[11];
  const float* ln2b = (const float*)d_in[12];
  const float* W1   = (const float*)d_in[13];
  const float* b1   = (const float*)d_in[14];
  const float* W2   = (const float*)d_in[15];
  const float* b2   = (const float*)d_in[16];

  char* ws = (char*)d_ws;
  const size_t MB = 1024 * 1024;
  u16*   wqkvt = (u16*)(ws + 0 * MB);      // 6 MB  (Wq^T | Wk^T | Wv^T rows)
  u16*   wot   = (u16*)(ws + 6 * MB);      // 2 MB
  u16*   w1t   = (u16*)(ws + 8 * MB);      // 8 MB
  u16*   w2t   = (u16*)(ws + 16 * MB);     // 8 MB
  float* bqkv  = (float*)(ws + 24 * MB);   // 12 KB
  u16*   hbuf  = (u16*)(ws + 25 * MB);     // 8 MB  (h2 overlays after QKV gemm)
  u16*   qkv   = (u16*)(ws + 33 * MB);     // 24 MB (mb overlays 33..65 after attn)
  u16*   vtb   = (u16*)(ws + 57 * MB);     // 8 MB
  u16*   yb    = (u16*)(ws + 65 * MB);     // 8 MB
  u16*   opart = (u16*)(ws + 73 * MB);     // 16 MB (2 splits x 8 MB)
  float* x2    = (float*)(ws + 73 * MB);   // 16 MB (written by Wo gemm, after combine)
  float* mlb   = (float*)(ws + 89 * MB);   // 1 MB
  u16*   h2    = hbuf;
  u16*   mb    = qkv;

  dim3 tb(32, 8);
  transpose4_kernel<<<dim3(32, 32, 4), tb, 0, stream>>>(Wq, Wk, Wv, Wo,
      wqkvt, wqkvt + 1024 * 1024, wqkvt + 2048 * 1024, wot);
  transpose_cast_kernel<<<dim3(128, 32), tb, 0, stream>>>(W1, w1t, 1024, 4096);
  transpose_cast_kernel<<<dim3(32, 128), tb, 0, stream>>>(W2, w2t, 4096, 1024);
  pack3_kernel<<<12, 256, 0, stream>>>(bq, bk, bv, bqkv);

  ln_kernel<<<4096, 256, 0, stream>>>(x, ln1g, ln1b, hbuf);

  // fused QKV (128^2, BK=32, 3 blocks/CU; EPI 3: q columns pre-scaled)
  gemmc_kernel<128, 128, 2, 2, 4, 3><<<dim3(32, 24), 256, 0, stream>>>(hbuf, wqkvt, bqkv, nullptr, qkv, 1024, 1024, 3072);

  transpose_v_kernel<<<dim3(64, 2, 32), tb, 0, stream>>>(qkv + 2048, vtb);

  // KV-split x2 attention + combine
  attn_kernel<<<dim3(16, 32, 2), 256, 0, stream>>>(qkv, qkv + 1024, vtb, opart, mlb);
  combine_kernel<<<4096, 256, 0, stream>>>(opart, mlb, yb);

  // Wo: [4096,1024] x [1024,1024]^T  (64x128, BK=32)
  gemmc_kernel<64, 128, 2, 2, 4, 1><<<dim3(64, 8), 256, 0, stream>>>(yb, wot, bo, x, x2, 1024, 1024, 1024);

  ln_kernel<<<4096, 256, 0, stream>>>(x2, ln2g, ln2b, h2);

  // W1: [4096,1024] x [4096,1024]^T  (128^2, BK=32, 4 blocks/CU, gelu)
  gemmc_kernel<128, 128, 2, 2, 4, 2><<<dim3(32, 32), 256, 0, stream>>>(h2, w1t, b1, nullptr, mb, 1024, 1024, 4096);

  // W2: [4096,4096] x [1024,4096]^T  (64x128, BK=32)
  gemmc_kernel<64, 128, 2, 2, 4, 1><<<dim3(64, 8), 256, 0, stream>>>(mb, w2t, b2, x2, (float*)d_out, 4096, 4096, 1024);
}

// Round 12
// 259.877 us; speedup vs baseline: 1.0494x; 1.0494x over previous
//
#include <hip/hip_runtime.h>
#include <math.h>

typedef unsigned short u16;
typedef unsigned int   u32;
using bf16x8 = __attribute__((ext_vector_type(8))) short;
using f32x4  = __attribute__((ext_vector_type(4))) float;
using f32x16 = __attribute__((ext_vector_type(16))) float;

static constexpr int Bb = 2, Tt = 2048, Cc = 1024, Hh = 16, Dd = 64;
static constexpr int QS = 3072;   // fused qkv row stride (u16 elements)
static constexpr float QSCALE = 0.125f * 1.44269504089f;  // folded into Q at QKV epilogue

__device__ __forceinline__ u16 f2bf(float f){
  u32 u = __builtin_bit_cast(u32, f);
  u += 0x7fffu + ((u >> 16) & 1u);
  return (u16)(u >> 16);
}
__device__ __forceinline__ float bf2f(u16 v){
  u32 u = (u32)v << 16;
  return __builtin_bit_cast(float, u);
}

__device__ __forceinline__ void gl2lds16(const void* g, void* l){
  __builtin_amdgcn_global_load_lds((const __attribute__((address_space(1))) void*)g,
                                   (__attribute__((address_space(3))) void*)l, 16, 0, 0);
}

template<int N> __device__ __forceinline__ void waitvm(){
  if constexpr (N == 0) asm volatile("s_waitcnt vmcnt(0)" ::: "memory");
  else if constexpr (N == 2) asm volatile("s_waitcnt vmcnt(2)" ::: "memory");
  else if constexpr (N == 4) asm volatile("s_waitcnt vmcnt(4)" ::: "memory");
  else if constexpr (N == 6) asm volatile("s_waitcnt vmcnt(6)" ::: "memory");
  else if constexpr (N == 8) asm volatile("s_waitcnt vmcnt(8)" ::: "memory");
}

__device__ __forceinline__ void barrier_pin(){
  __builtin_amdgcn_s_barrier();
  __builtin_amdgcn_sched_barrier(0);
}

__device__ __forceinline__ f32x4 mfma16(bf16x8 a, bf16x8 b, f32x4 c){
  return __builtin_amdgcn_mfma_f32_16x16x32_bf16(a, b, c, 0, 0, 0);
}
__device__ __forceinline__ f32x16 mfma32(bf16x8 a, bf16x8 b, f32x16 c){
  return __builtin_amdgcn_mfma_f32_32x32x16_bf16(a, b, c, 0, 0, 0);
}

__device__ __forceinline__ float exp2f_fast(float x){
#if __has_builtin(__builtin_amdgcn_exp2f)
  return __builtin_amdgcn_exp2f(x);
#else
  return __expf(x * 0.69314718056f);
#endif
}

__device__ __forceinline__ float gelu_f(float x){
  return 0.5f * x * (1.0f + erff(x * 0.70710678118654752f));
}

// swap lanes[32:63] of a with lanes[0:31] of b (both results useful)
__device__ __forceinline__ void plane_swap(u32& a, u32& b){
  asm("v_permlane32_swap_b32 %0, %1" : "+v"(a), "+v"(b));
}
__device__ __forceinline__ u32 cvtpk_bf16(float lo, float hi){
  u32 r;
  asm("v_cvt_pk_bf16_f32 %0, %1, %2" : "=v"(r) : "v"(lo), "v"(hi));
  return r;
}

// ---------------- LayerNorm: fp32 row -> bf16 row ----------------
__global__ __launch_bounds__(256) void ln_kernel(const float* __restrict__ x,
    const float* __restrict__ g, const float* __restrict__ b, u16* __restrict__ out)
{
  int row = blockIdx.x;
  int tid = threadIdx.x;
  const float4* xr = (const float4*)(x + (size_t)row * Cc);
  float4 v = xr[tid];
  float s  = v.x + v.y + v.z + v.w;
  float s2 = v.x*v.x + v.y*v.y + v.z*v.z + v.w*v.w;
  #pragma unroll
  for (int off = 1; off < 64; off <<= 1){ s += __shfl_xor(s, off); s2 += __shfl_xor(s2, off); }
  __shared__ float red[8];
  int wid = tid >> 6;
  if ((tid & 63) == 0){ red[wid] = s; red[4 + wid] = s2; }
  __syncthreads();
  s  = red[0] + red[1] + red[2] + red[3];
  s2 = red[4] + red[5] + red[6] + red[7];
  float mu   = s * (1.0f / Cc);
  float var  = s2 * (1.0f / Cc) - mu * mu;
  float rstd = rsqrtf(var + 1e-5f);
  const float4 gg = ((const float4*)g)[tid];
  const float4 bb = ((const float4*)b)[tid];
  ushort4 o;
  o.x = f2bf((v.x - mu) * rstd * gg.x + bb.x);
  o.y = f2bf((v.y - mu) * rstd * gg.y + bb.y);
  o.z = f2bf((v.z - mu) * rstd * gg.z + bb.z);
  o.w = f2bf((v.w - mu) * rstd * gg.w + bb.w);
  *(ushort4*)(out + (size_t)row * Cc + tid * 4) = o;
}

// ---------------- transpose + cast: W[K][N] fp32 -> WT[N][K] bf16 ----------------
__global__ __launch_bounds__(256) void transpose_cast_kernel(const float* __restrict__ in,
    u16* __restrict__ out, int R, int Ccols)
{
  __shared__ float tile[32][33];
  int tx = threadIdx.x, ty = threadIdx.y;
  int c0 = blockIdx.x * 32, r0 = blockIdx.y * 32;
  #pragma unroll
  for (int j = 0; j < 4; j++) tile[ty + j*8][tx] = in[(size_t)(r0 + ty + j*8) * Ccols + c0 + tx];
  __syncthreads();
  #pragma unroll
  for (int j = 0; j < 4; j++) out[(size_t)(c0 + ty + j*8) * R + r0 + tx] = f2bf(tile[tx][ty + j*8]);
}

// ---------------- 4x fused 1024x1024 transpose+cast ----------------
__global__ __launch_bounds__(256) void transpose4_kernel(
    const float* __restrict__ s0, const float* __restrict__ s1,
    const float* __restrict__ s2, const float* __restrict__ s3,
    u16* __restrict__ d0, u16* __restrict__ d1, u16* __restrict__ d2, u16* __restrict__ d3)
{
  __shared__ float tile[32][33];
  int z = blockIdx.z;
  const float* in = (z == 0) ? s0 : (z == 1) ? s1 : (z == 2) ? s2 : s3;
  u16* out        = (z == 0) ? d0 : (z == 1) ? d1 : (z == 2) ? d2 : d3;
  int tx = threadIdx.x, ty = threadIdx.y;
  int c0 = blockIdx.x * 32, r0 = blockIdx.y * 32;
  #pragma unroll
  for (int j = 0; j < 4; j++) tile[ty + j*8][tx] = in[(size_t)(r0 + ty + j*8) * 1024 + c0 + tx];
  __syncthreads();
  #pragma unroll
  for (int j = 0; j < 4; j++) out[(size_t)(c0 + ty + j*8) * 1024 + r0 + tx] = f2bf(tile[tx][ty + j*8]);
}

// ---------------- pack 3 bias vectors into one [3072] ----------------
__global__ __launch_bounds__(256) void pack3_kernel(const float* __restrict__ a,
    const float* __restrict__ b, const float* __restrict__ c, float* __restrict__ o)
{
  int i = blockIdx.x * 256 + threadIdx.x;
  float v = (i < 1024) ? a[i] : (i < 2048 ? b[i - 1024] : c[i - 2048]);
  o[i] = v;
}

// ---------------- v slice of qkv (stride QS) -> vt (B,H,D,T) bf16 ----------------
__global__ __launch_bounds__(256) void transpose_v_kernel(const u16* __restrict__ v, u16* __restrict__ vt)
{
  __shared__ u16 tile[32][33];
  int tx = threadIdx.x, ty = threadIdx.y;
  int bh = blockIdx.z; int b = bh >> 4, h = bh & 15;
  int t0 = blockIdx.x * 32, d0 = blockIdx.y * 32;
  const u16* src = v + (size_t)b * Tt * QS + h * Dd;
  #pragma unroll
  for (int j = 0; j < 4; j++) tile[ty + j*8][tx] = src[(size_t)(t0 + ty + j*8) * QS + d0 + tx];
  __syncthreads();
  u16* dst = vt + (size_t)bh * Dd * Tt;
  #pragma unroll
  for (int j = 0; j < 4; j++) dst[(size_t)(d0 + ty + j*8) * Tt + t0 + tx] = tile[tx][ty + j*8];
}

// ============ 8-phase 256x256 GEMM (T3+T4+T2+T5+T1) -- QKV / W1 ============
// (R10-exact; verified passing at absmax 0.1016)
template<int EPI>
__global__ __launch_bounds__(512, 2) void gemm8p_kernel(
    const u16* __restrict__ A, const u16* __restrict__ BT,
    const float* __restrict__ bias, void* __restrict__ out,
    int K, int ldA, int ldOut)
{
  __shared__ alignas(16) u16 AsU[2 * 2 * 256 * 32];
  __shared__ alignas(16) u16 BsU[2 * 2 * 256 * 32];

  const int tid  = threadIdx.x;
  const int lane = tid & 63, wid = tid >> 6;
  const int l15  = lane & 15, lg = lane >> 4;

  const int gx  = gridDim.x;
  const int lin = blockIdx.x + gx * blockIdx.y;
  const int nwg = gx * gridDim.y;
  const int wl  = (lin & 7) * (nwg >> 3) + (lin >> 3);
  const int rowBase = (wl % gx) * 256, colBase = (wl / gx) * 256;

  const int wr = wid >> 2, wc = wid & 3;

  f32x4 acc[8][4] = {};

  auto stageH = [&](int which, int k0n, int buf){
    const u16* src = (which & 1) ? BT : A;
    const int  ldS = (which & 1) ? K : ldA;
    const int  bse = (which & 1) ? colBase : rowBase;
    const int  kh  = which >> 1;
    u16* lds = ((which & 1) ? BsU : AsU) + buf * 16384 + kh * 8192;
    #pragma unroll
    for (int j = 0; j < 2; j++){
      int s = tid + 512 * j;
      int row = s >> 2, p = s & 3;
      int w = p ^ ((row >> 1) & 3);
      gl2lds16(src + (size_t)(bse + row) * ldS + k0n + kh * 32 + w * 8, lds + s * 8);
    }
  };

  auto ldsA = [&](int buf, int kh, int pm, bf16x8* a){
    const u16* p = AsU + buf * 16384 + kh * 8192;
    #pragma unroll
    for (int mi = 0; mi < 4; mi++){
      int r = wr * 128 + pm * 64 + mi * 16 + l15;
      a[mi] = *(const bf16x8*)(p + r * 32 + ((lg ^ ((r >> 1) & 3)) << 3));
    }
  };
  auto ldsB = [&](int buf, int kh, bf16x8* b){
    const u16* p = BsU + buf * 16384 + kh * 8192;
    #pragma unroll
    for (int ni = 0; ni < 4; ni++){
      int r = wc * 64 + ni * 16 + l15;
      b[ni] = *(const bf16x8*)(p + r * 32 + ((lg ^ ((r >> 1) & 3)) << 3));
    }
  };
  auto mfmaQ = [&](int pm, const bf16x8* a, const bf16x8* b){
    __builtin_amdgcn_s_setprio(1);
    #pragma unroll
    for (int mi = 0; mi < 4; mi++)
      #pragma unroll
      for (int ni = 0; ni < 4; ni++)
        acc[pm * 4 + mi][ni] = mfma16(a[mi], b[ni], acc[pm * 4 + mi][ni]);
    __builtin_amdgcn_s_setprio(0);
  };

  stageH(0, 0, 0); stageH(1, 0, 0); stageH(2, 0, 0); stageH(3, 0, 0);
  waitvm<4>();
  __builtin_amdgcn_s_barrier();

  const int nt = K >> 6;
  bf16x8 a[4], b[4];
  for (int t = 0; t < nt - 1; ++t){
    const int cur = t & 1, nxt = cur ^ 1;
    const int kn = (t + 1) << 6;
    ldsA(cur, 0, 0, a); ldsB(cur, 0, b); stageH(0, kn, nxt);
    __builtin_amdgcn_s_barrier();
    mfmaQ(0, a, b);
    __builtin_amdgcn_s_barrier();
    ldsA(cur, 0, 1, a); stageH(1, kn, nxt);
    __builtin_amdgcn_s_barrier();
    mfmaQ(1, a, b);
    waitvm<6>();
    __builtin_amdgcn_s_barrier();
    ldsA(cur, 1, 0, a); ldsB(cur, 1, b); stageH(2, kn, nxt);
    __builtin_amdgcn_s_barrier();
    mfmaQ(0, a, b);
    waitvm<6>();
    __builtin_amdgcn_s_barrier();
    ldsA(cur, 1, 1, a); stageH(3, kn, nxt);
    __builtin_amdgcn_s_barrier();
    mfmaQ(1, a, b);
    waitvm<4>();
    __builtin_amdgcn_s_barrier();
  }
  {
    const int cur = (nt - 1) & 1;
    ldsA(cur, 0, 0, a); ldsB(cur, 0, b);
    __builtin_amdgcn_s_barrier();
    mfmaQ(0, a, b);
    __builtin_amdgcn_s_barrier();
    ldsA(cur, 0, 1, a);
    __builtin_amdgcn_s_barrier();
    mfmaQ(1, a, b);
    waitvm<2>();
    __builtin_amdgcn_s_barrier();
    ldsA(cur, 1, 0, a); ldsB(cur, 1, b);
    __builtin_amdgcn_s_barrier();
    mfmaQ(0, a, b);
    waitvm<0>();
    __builtin_amdgcn_s_barrier();
    ldsA(cur, 1, 1, a);
    __builtin_amdgcn_s_barrier();
    mfmaQ(1, a, b);
  }

  #pragma unroll
  for (int mi = 0; mi < 8; mi++){
    #pragma unroll
    for (int ni = 0; ni < 4; ni++){
      int row = rowBase + wr * 128 + mi * 16 + lg * 4;
      int col = colBase + wc * 64 + ni * 16 + l15;
      float bc = bias[col];
      #pragma unroll
      for (int r = 0; r < 4; r++){
        float val = acc[mi][ni][r] + bc;
        size_t idx = (size_t)(row + r) * ldOut + col;
        if constexpr (EPI == 2) ((u16*)out)[idx] = f2bf(gelu_f(val));
        else                    ((u16*)out)[idx] = f2bf(col < 1024 ? val * QSCALE : val);
      }
    }
  }
}

// ---------------- counted-vmcnt GEMM, BK=64 (T4 + T2 + T1) -- Wo / W2 ----------------
// 64x64 tiles -> grid 1024 blocks -> 4 blocks/CU resident (occupancy lever).
// EPI 1: f32 out (+bias+residual)
template<int BM, int BN, int WM, int WN, int WPEU, int EPI>
__global__ __launch_bounds__(WM * WN * 64, WPEU) void gemmc_kernel(
    const u16* __restrict__ A, const u16* __restrict__ BT,
    const float* __restrict__ bias, const float* __restrict__ resid,
    void* __restrict__ out, int K, int ldA, int ldOut)
{
  constexpr int THREADS = WM * WN * 64;
  constexpr int MF = (BM / WM) / 16;
  constexpr int NF = (BN / WN) / 16;
  constexpr int AG = (BM * 8) / THREADS;
  constexpr int BG = (BN * 8) / THREADS;
  constexpr int NLOADS = AG + BG;

  __shared__ alignas(16) u16 As[2][BM * 64];
  __shared__ alignas(16) u16 Bs[2][BN * 64];

  const int tid  = threadIdx.x;
  const int lane = tid & 63, wid = tid >> 6;
  const int l15  = lane & 15, lg = lane >> 4;

  const int gx  = gridDim.x;
  const int lin = blockIdx.x + gx * blockIdx.y;
  const int nwg = gx * gridDim.y;
  const int wl  = (lin & 7) * (nwg >> 3) + (lin >> 3);
  const int rowBase = (wl % gx) * BM, colBase = (wl / gx) * BN;

  const int wr = wid / WN, wc = wid % WN;

  f32x4 acc[MF][NF] = {};

  auto stage = [&](int buf, int k0){
    #pragma unroll
    for (int j = 0; j < AG; j++){
      int g = tid + THREADS * j;
      int row = g >> 3, ch = (g & 7) ^ (row & 7);
      gl2lds16(A + (size_t)(rowBase + row) * ldA + k0 + ch * 8,
               (u16*)As[buf] + g * 8);
    }
    #pragma unroll
    for (int j = 0; j < BG; j++){
      int g = tid + THREADS * j;
      int row = g >> 3, ch = (g & 7) ^ (row & 7);
      gl2lds16(BT + (size_t)(colBase + row) * K + k0 + ch * 8,
               (u16*)Bs[buf] + g * 8);
    }
  };

  stage(0, 0);
  const int nt = K >> 6;
  int cur = 0;
  for (int t = 0; t < nt; ++t, cur ^= 1){
    if (t + 1 < nt){ stage(cur ^ 1, (t + 1) << 6); waitvm<NLOADS>(); }
    else           { waitvm<0>(); }
    __builtin_amdgcn_s_barrier();
    __builtin_amdgcn_sched_barrier(0);

    const u16* Asb = (const u16*)As[cur];
    const u16* Bsb = (const u16*)Bs[cur];

    bf16x8 bfr[NF][2];
    #pragma unroll
    for (int ni = 0; ni < NF; ni++){
      int r = wc * (BN / WN) + ni * 16 + l15;
      bfr[ni][0] = *(const bf16x8*)(Bsb + r * 64 + ((lg       ^ (r & 7)) << 3));
      bfr[ni][1] = *(const bf16x8*)(Bsb + r * 64 + (((4 + lg) ^ (r & 7)) << 3));
    }
    #pragma unroll
    for (int mi = 0; mi < MF; mi++){
      int r = wr * (BM / WM) + mi * 16 + l15;
      bf16x8 a0 = *(const bf16x8*)(Asb + r * 64 + ((lg       ^ (r & 7)) << 3));
      bf16x8 a1 = *(const bf16x8*)(Asb + r * 64 + (((4 + lg) ^ (r & 7)) << 3));
      __builtin_amdgcn_s_setprio(1);
      #pragma unroll
      for (int ni = 0; ni < NF; ni++){
        acc[mi][ni] = mfma16(a0, bfr[ni][0], acc[mi][ni]);
        acc[mi][ni] = mfma16(a1, bfr[ni][1], acc[mi][ni]);
      }
      __builtin_amdgcn_s_setprio(0);
    }

    __builtin_amdgcn_sched_barrier(0);
    __builtin_amdgcn_s_barrier();
  }

  #pragma unroll
  for (int mi = 0; mi < MF; mi++){
    #pragma unroll
    for (int ni = 0; ni < NF; ni++){
      int row = rowBase + wr * (BM / WM) + mi * 16 + lg * 4;
      int col = colBase + wc * (BN / WN) + ni * 16 + l15;
      float bc = bias[col];
      #pragma unroll
      for (int r = 0; r < 4; r++){
        float val = acc[mi][ni][r] + bc;
        size_t idx = (size_t)(row + r) * ldOut + col;
        if constexpr (EPI == 1) ((float*)out)[idx] = val + resid[idx];
        else                    ((u16*)out)[idx]   = f2bf(val);
      }
    }
  }
}

// ---------------- Flash attention, swapped 32x32, KV-split x2 ----------------
__global__ __launch_bounds__(256, 4) void attn_kernel(const u16* __restrict__ q, const u16* __restrict__ k,
    const u16* __restrict__ vt, u16* __restrict__ opart, float* __restrict__ ml)
{
  __shared__ alignas(16) u16 Ks[2][64 * 64];
  __shared__ alignas(16) u16 Vs[2][64 * 64];
  int tid  = threadIdx.x;
  int lane = tid & 63, wid = tid >> 6;
  int l31  = lane & 31, hi = lane >> 5;

  int lin = blockIdx.x + 16 * blockIdx.y;
  int wl  = (lin & 7) * 64 + (lin >> 3);
  int qt  = wl & 15, bh = wl >> 4;
  int b = bh >> 4, h = bh & 15;
  int split = blockIdx.z;
  int kt0 = split * (Tt / 2);

  int qglob = qt * 128 + wid * 32 + l31;

  const u16* qp = q + ((size_t)b * Tt + qglob) * QS + h * Dd + hi * 8;
  bf16x8 qf[4];
  #pragma unroll
  for (int s = 0; s < 4; s++) qf[s] = *(const bf16x8*)(qp + s * 16);

  const u16* kbase = k  + (size_t)b * Tt * QS + h * Dd;
  const u16* vbase = vt + (size_t)bh * Dd * Tt;

  f32x16 yacc[2] = {};
  float m2 = -1e30f, lsum = 0.f;

  int g0 = tid, g1 = tid + 256;
  int r0 = g0 >> 3, cb0 = (g0 & 7) ^ (r0 & 7);
  int r1 = g1 >> 3, cb1 = (g1 & 7) ^ (r1 & 7);

  auto stageKV = [&](int buf, int kt){
    gl2lds16(kbase + (size_t)(kt + r0) * QS + cb0 * 8, (u16*)Ks[buf] + wid * 512);
    gl2lds16(kbase + (size_t)(kt + r1) * QS + cb1 * 8, (u16*)Ks[buf] + 2048 + wid * 512);
    gl2lds16(vbase + (size_t)r0 * Tt + kt + cb0 * 8,   (u16*)Vs[buf] + wid * 512);
    gl2lds16(vbase + (size_t)r1 * Tt + kt + cb1 * 8,   (u16*)Vs[buf] + 2048 + wid * 512);
  };

  stageKV(0, kt0);
  int cur = 0;
  for (int kt = kt0; kt < kt0 + Tt / 2; kt += 64) {
    if (kt + 64 < kt0 + Tt / 2) { stageKV(cur ^ 1, kt + 64); waitvm<4>(); }
    else                        { waitvm<0>(); }
    barrier_pin();

    const u16* Ksb = (const u16*)Ks[cur];
    const u16* Vsb = (const u16*)Vs[cur];
    int rx = l31 & 7;

    f32x16 st[2] = {};
    __builtin_amdgcn_s_setprio(1);
    #pragma unroll
    for (int nb = 0; nb < 2; nb++){
      const u16* krow = Ksb + (nb * 32 + l31) * 64;
      #pragma unroll
      for (int s = 0; s < 4; s++){
        bf16x8 kf = *(const bf16x8*)(krow + (((s * 2 + hi) ^ rx) << 3));
        st[nb] = mfma32(kf, qf[s], st[nb]);
      }
    }
    __builtin_amdgcn_s_setprio(0);

    float tm[16];
    #pragma unroll
    for (int i = 0; i < 16; i++) tm[i] = fmaxf(st[0][i], st[1][i]);
    #pragma unroll
    for (int w = 8; w; w >>= 1)
      #pragma unroll
      for (int i = 0; i < w; i++) tm[i] = fmaxf(tm[i], tm[i + w]);
    u32 ma = __builtin_bit_cast(u32, tm[0]), mb = ma;
    plane_swap(ma, mb);
    float mx = fmaxf(__builtin_bit_cast(float, ma), __builtin_bit_cast(float, mb));

    float mnew = fmaxf(m2, mx);
    float alpha = exp2f_fast(m2 - mnew);
    m2 = mnew;

    #pragma unroll
    for (int nb = 0; nb < 2; nb++)
      #pragma unroll
      for (int i = 0; i < 16; i++)
        st[nb][i] = exp2f_fast(st[nb][i] - m2);

    float ts[16];
    #pragma unroll
    for (int i = 0; i < 16; i++) ts[i] = st[0][i] + st[1][i];
    #pragma unroll
    for (int w = 8; w; w >>= 1)
      #pragma unroll
      for (int i = 0; i < w; i++) ts[i] += ts[i + w];
    u32 sa = __builtin_bit_cast(u32, ts[0]), sb = sa;
    plane_swap(sa, sb);
    lsum = lsum * alpha + __builtin_bit_cast(float, sa) + __builtin_bit_cast(float, sb);

    #pragma unroll
    for (int nd = 0; nd < 2; nd++)
      #pragma unroll
      for (int i = 0; i < 16; i++) yacc[nd][i] *= alpha;

    bf16x8 pb[4];
    #pragma unroll
    for (int nb = 0; nb < 2; nb++){
      u32 c[8];
      #pragma unroll
      for (int i = 0; i < 8; i++) c[i] = cvtpk_bf16(st[nb][2 * i], st[nb][2 * i + 1]);
      plane_swap(c[0], c[2]); plane_swap(c[1], c[3]);
      plane_swap(c[4], c[6]); plane_swap(c[5], c[7]);
      u32 f0[4] = {c[0], c[1], c[2], c[3]};
      u32 f1[4] = {c[4], c[5], c[6], c[7]};
      pb[nb * 2 + 0] = *(bf16x8*)f0;
      pb[nb * 2 + 1] = *(bf16x8*)f1;
    }

    __builtin_amdgcn_s_setprio(1);
    #pragma unroll
    for (int nd = 0; nd < 2; nd++){
      const u16* vrow = Vsb + (nd * 32 + l31) * 64;
      #pragma unroll
      for (int ks = 0; ks < 4; ks++){
        bf16x8 vf = *(const bf16x8*)(vrow + (((ks * 2 + hi) ^ rx) << 3));
        yacc[nd] = mfma32(vf, pb[ks], yacc[nd]);
      }
    }
    __builtin_amdgcn_s_setprio(0);

    __builtin_amdgcn_sched_barrier(0);
    barrier_pin();
    cur ^= 1;
  }

  float inv = 1.0f / lsum;
  u16* op = opart + ((size_t)split * (Bb * Tt) + (size_t)b * Tt + qglob) * Cc + h * Dd;
  #pragma unroll
  for (int nd = 0; nd < 2; nd++){
    #pragma unroll
    for (int g = 0; g < 4; g++){
      ushort4 o;
      o.x = f2bf(yacc[nd][g * 4 + 0] * inv);
      o.y = f2bf(yacc[nd][g * 4 + 1] * inv);
      o.z = f2bf(yacc[nd][g * 4 + 2] * inv);
      o.w = f2bf(yacc[nd][g * 4 + 3] * inv);
      *(ushort4*)(op + nd * 32 + g * 8 + hi * 4) = o;
    }
  }
  if (hi == 0){
    float* mlp = ml + (((size_t)split * (Bb * Tt) + (size_t)b * Tt + qglob) * Hh + h) * 2;
    mlp[0] = m2; mlp[1] = lsum;
  }
}

// ---------------- combine 2 KV-splits (convex combination of normalized partials) ----
__global__ __launch_bounds__(256) void combine_kernel(const u16* __restrict__ opart,
    const float* __restrict__ ml, u16* __restrict__ y)
{
  int row = blockIdx.x;
  int d0  = threadIdx.x * 4;
  int h   = d0 >> 6;
  const float* p0 = ml + ((size_t)row * Hh + h) * 2;
  const float* p1 = ml + (((size_t)(Bb * Tt) + row) * Hh + h) * 2;
  float m0 = p0[0], l0 = p0[1], m1 = p1[0], l1 = p1[1];
  float M  = fmaxf(m0, m1);
  float u0 = l0 * exp2f_fast(m0 - M), u1 = l1 * exp2f_fast(m1 - M);
  float inv = 1.0f / (u0 + u1);
  float w0 = u0 * inv, w1 = u1 * inv;
  ushort4 a = *(const ushort4*)(opart + (size_t)row * Cc + d0);
  ushort4 c = *(const ushort4*)(opart + ((size_t)(Bb * Tt) + row) * Cc + d0);
  ushort4 o;
  o.x = f2bf(bf2f(a.x) * w0 + bf2f(c.x) * w1);
  o.y = f2bf(bf2f(a.y) * w0 + bf2f(c.y) * w1);
  o.z = f2bf(bf2f(a.z) * w0 + bf2f(c.z) * w1);
  o.w = f2bf(bf2f(a.w) * w0 + bf2f(c.w) * w1);
  *(ushort4*)(y + (size_t)row * Cc + d0) = o;
}

extern "C" void kernel_launch(void* const* d_in, const int* in_sizes, int n_in,
                              void* d_out, int out_size, void* d_ws, size_t ws_size,
                              hipStream_t stream)
{
  (void)in_sizes; (void)n_in; (void)out_size; (void)ws_size;
  const float* x    = (const float*)d_in[0];
  const float* Wq   = (const float*)d_in[1];
  const float* bq   = (const float*)d_in[2];
  const float* Wk   = (const float*)d_in[3];
  const float* bk   = (const float*)d_in[4];
  const float* Wv   = (const float*)d_in[5];
  const float* bv   = (const float*)d_in[6];
  const float* Wo   = (const float*)d_in[7];
  const float* bo   = (const float*)d_in[8];
  const float* ln1g = (const float*)d_in[9];
  const float* ln1b = (const float*)d_in[10];
  const float* ln2g = (const float*)d_in[11];
  const float* ln2b = (const float*)d_in[12];
  const float* W1   = (const float*)d_in[13];
  const float* b1   = (const float*)d_in[14];
  const float* W2   = (const float*)d_in[15];
  const float* b2   = (const float*)d_in[16];

  char* ws = (char*)d_ws;
  const size_t MB = 1024 * 1024;
  u16*   wqkvt = (u16*)(ws + 0 * MB);      // 6 MB  (Wq^T | Wk^T | Wv^T rows)
  u16*   wot   = (u16*)(ws + 6 * MB);      // 2 MB
  u16*   w1t   = (u16*)(ws + 8 * MB);      // 8 MB
  u16*   w2t   = (u16*)(ws + 16 * MB);     // 8 MB
  float* bqkv  = (float*)(ws + 24 * MB);   // 12 KB
  u16*   hbuf  = (u16*)(ws + 25 * MB);     // 8 MB  (h2 overlays after QKV gemm)
  u16*   qkv   = (u16*)(ws + 33 * MB);     // 24 MB (mb overlays 33..65 after attn)
  u16*   vtb   = (u16*)(ws + 57 * MB);     // 8 MB
  u16*   yb    = (u16*)(ws + 65 * MB);     // 8 MB
  u16*   opart = (u16*)(ws + 73 * MB);     // 16 MB (2 splits x 8 MB)
  float* x2    = (float*)(ws + 73 * MB);   // 16 MB (written by Wo gemm, after combine)
  float* mlb   = (float*)(ws + 89 * MB);   // 1 MB
  u16*   h2    = hbuf;
  u16*   mb    = qkv;

  dim3 tb(32, 8);
  transpose4_kernel<<<dim3(32, 32, 4), tb, 0, stream>>>(Wq, Wk, Wv, Wo,
      wqkvt, wqkvt + 1024 * 1024, wqkvt + 2048 * 1024, wot);
  transpose_cast_kernel<<<dim3(128, 32), tb, 0, stream>>>(W1, w1t, 1024, 4096);
  transpose_cast_kernel<<<dim3(32, 128), tb, 0, stream>>>(W2, w2t, 4096, 1024);
  pack3_kernel<<<12, 256, 0, stream>>>(bq, bk, bv, bqkv);

  ln_kernel<<<4096, 256, 0, stream>>>(x, ln1g, ln1b, hbuf);

  // fused QKV (8-phase 256^2; EPI 3: q columns pre-scaled by QSCALE)
  gemm8p_kernel<3><<<dim3(16, 12), 512, 0, stream>>>(hbuf, wqkvt, bqkv, qkv, 1024, 1024, 3072);

  transpose_v_kernel<<<dim3(64, 2, 32), tb, 0, stream>>>(qkv + 2048, vtb);

  // KV-split x2 attention + combine
  attn_kernel<<<dim3(16, 32, 2), 256, 0, stream>>>(qkv, qkv + 1024, vtb, opart, mlb);
  combine_kernel<<<4096, 256, 0, stream>>>(opart, mlb, yb);

  // Wo: [4096,1024] x [1024,1024]^T  (64x64, BK=64, 1024 blocks = 4/CU)
  gemmc_kernel<64, 64, 2, 2, 4, 1><<<dim3(64, 16), 256, 0, stream>>>(yb, wot, bo, x, x2, 1024, 1024, 1024);

  ln_kernel<<<4096, 256, 0, stream>>>(x2, ln2g, ln2b, h2);

  // W1: [4096,1024] x [4096,1024]^T (8-phase 256^2, gelu)
  gemm8p_kernel<2><<<dim3(16, 16), 512, 0, stream>>>(h2, w1t, b1, mb, 1024, 1024, 4096);

  // W2: [4096,4096] x [1024,4096]^T  (64x64, BK=64, 1024 blocks = 4/CU)
  gemmc_kernel<64, 64, 2, 2, 4, 1><<<dim3(64, 16), 256, 0, stream>>>(mb, w2t, b2, x2, (float*)d_out, 4096, 4096, 1024);
}

// Round 13
// 246.668 us; speedup vs baseline: 1.1056x; 1.0535x over previous
//
#include <hip/hip_runtime.h>
#include <math.h>

typedef unsigned short u16;
typedef unsigned int   u32;
using bf16x8 = __attribute__((ext_vector_type(8))) short;
using f32x4  = __attribute__((ext_vector_type(4))) float;
using f32x16 = __attribute__((ext_vector_type(16))) float;

static constexpr int Bb = 2, Tt = 2048, Cc = 1024, Hh = 16, Dd = 64;
static constexpr int QS = 3072;   // fused qkv row stride (u16 elements)
static constexpr float QSCALE = 0.125f * 1.44269504089f;  // folded into Q at QKV epilogue

__device__ __forceinline__ u16 f2bf(float f){
  u32 u = __builtin_bit_cast(u32, f);
  u += 0x7fffu + ((u >> 16) & 1u);
  return (u16)(u >> 16);
}
__device__ __forceinline__ float bf2f(u16 v){
  u32 u = (u32)v << 16;
  return __builtin_bit_cast(float, u);
}

__device__ __forceinline__ void gl2lds16(const void* g, void* l){
  __builtin_amdgcn_global_load_lds((const __attribute__((address_space(1))) void*)g,
                                   (__attribute__((address_space(3))) void*)l, 16, 0, 0);
}

template<int N> __device__ __forceinline__ void waitvm(){
  if constexpr (N == 0) asm volatile("s_waitcnt vmcnt(0)" ::: "memory");
  else if constexpr (N == 4) asm volatile("s_waitcnt vmcnt(4)" ::: "memory");
  else if constexpr (N == 8) asm volatile("s_waitcnt vmcnt(8)" ::: "memory");
}

__device__ __forceinline__ void barrier_pin(){
  __builtin_amdgcn_s_barrier();
  __builtin_amdgcn_sched_barrier(0);
}

__device__ __forceinline__ f32x4 mfma16(bf16x8 a, bf16x8 b, f32x4 c){
  return __builtin_amdgcn_mfma_f32_16x16x32_bf16(a, b, c, 0, 0, 0);
}
__device__ __forceinline__ f32x16 mfma32(bf16x8 a, bf16x8 b, f32x16 c){
  return __builtin_amdgcn_mfma_f32_32x32x16_bf16(a, b, c, 0, 0, 0);
}

__device__ __forceinline__ float exp2f_fast(float x){
#if __has_builtin(__builtin_amdgcn_exp2f)
  return __builtin_amdgcn_exp2f(x);
#else
  return __expf(x * 0.69314718056f);
#endif
}

__device__ __forceinline__ float gelu_f(float x){
  return 0.5f * x * (1.0f + erff(x * 0.70710678118654752f));
}

__device__ __forceinline__ void plane_swap(u32& a, u32& b){
  asm("v_permlane32_swap_b32 %0, %1" : "+v"(a), "+v"(b));
}
__device__ __forceinline__ u32 cvtpk_bf16(float lo, float hi){
  u32 r;
  asm("v_cvt_pk_bf16_f32 %0, %1, %2" : "=v"(r) : "v"(lo), "v"(hi));
  return r;
}

__device__ __forceinline__ bf16x8 ldlds(const u16* p){ return *(const bf16x8*)p; }

// ---------------- LayerNorm: fp32 row -> bf16 row ----------------
__global__ __launch_bounds__(256) void ln_kernel(const float* __restrict__ x,
    const float* __restrict__ g, const float* __restrict__ b, u16* __restrict__ out)
{
  int row = blockIdx.x;
  int tid = threadIdx.x;
  const float4* xr = (const float4*)(x + (size_t)row * Cc);
  float4 v = xr[tid];
  float s  = v.x + v.y + v.z + v.w;
  float s2 = v.x*v.x + v.y*v.y + v.z*v.z + v.w*v.w;
  #pragma unroll
  for (int off = 1; off < 64; off <<= 1){ s += __shfl_xor(s, off); s2 += __shfl_xor(s2, off); }
  __shared__ float red[8];
  int wid = tid >> 6;
  if ((tid & 63) == 0){ red[wid] = s; red[4 + wid] = s2; }
  __syncthreads();
  s  = red[0] + red[1] + red[2] + red[3];
  s2 = red[4] + red[5] + red[6] + red[7];
  float mu   = s * (1.0f / Cc);
  float var  = s2 * (1.0f / Cc) - mu * mu;
  float rstd = rsqrtf(var + 1e-5f);
  const float4 gg = ((const float4*)g)[tid];
  const float4 bb = ((const float4*)b)[tid];
  ushort4 o;
  o.x = f2bf((v.x - mu) * rstd * gg.x + bb.x);
  o.y = f2bf((v.y - mu) * rstd * gg.y + bb.y);
  o.z = f2bf((v.z - mu) * rstd * gg.z + bb.z);
  o.w = f2bf((v.w - mu) * rstd * gg.w + bb.w);
  *(ushort4*)(out + (size_t)row * Cc + tid * 4) = o;
}

// ---------------- transpose + cast: W[K][N] fp32 -> WT[N][K] bf16 ----------------
__global__ __launch_bounds__(256) void transpose_cast_kernel(const float* __restrict__ in,
    u16* __restrict__ out, int R, int Ccols)
{
  __shared__ float tile[32][33];
  int tx = threadIdx.x, ty = threadIdx.y;
  int c0 = blockIdx.x * 32, r0 = blockIdx.y * 32;
  #pragma unroll
  for (int j = 0; j < 4; j++) tile[ty + j*8][tx] = in[(size_t)(r0 + ty + j*8) * Ccols + c0 + tx];
  __syncthreads();
  #pragma unroll
  for (int j = 0; j < 4; j++) out[(size_t)(c0 + ty + j*8) * R + r0 + tx] = f2bf(tile[tx][ty + j*8]);
}

// ---------------- 4x fused 1024x1024 transpose+cast ----------------
__global__ __launch_bounds__(256) void transpose4_kernel(
    const float* __restrict__ s0, const float* __restrict__ s1,
    const float* __restrict__ s2, const float* __restrict__ s3,
    u16* __restrict__ d0, u16* __restrict__ d1, u16* __restrict__ d2, u16* __restrict__ d3)
{
  __shared__ float tile[32][33];
  int z = blockIdx.z;
  const float* in = (z == 0) ? s0 : (z == 1) ? s1 : (z == 2) ? s2 : s3;
  u16* out        = (z == 0) ? d0 : (z == 1) ? d1 : (z == 2) ? d2 : d3;
  int tx = threadIdx.x, ty = threadIdx.y;
  int c0 = blockIdx.x * 32, r0 = blockIdx.y * 32;
  #pragma unroll
  for (int j = 0; j < 4; j++) tile[ty + j*8][tx] = in[(size_t)(r0 + ty + j*8) * 1024 + c0 + tx];
  __syncthreads();
  #pragma unroll
  for (int j = 0; j < 4; j++) out[(size_t)(c0 + ty + j*8) * 1024 + r0 + tx] = f2bf(tile[tx][ty + j*8]);
}

// ---------------- pack 3 bias vectors into one [3072] ----------------
__global__ __launch_bounds__(256) void pack3_kernel(const float* __restrict__ a,
    const float* __restrict__ b, const float* __restrict__ c, float* __restrict__ o)
{
  int i = blockIdx.x * 256 + threadIdx.x;
  float v = (i < 1024) ? a[i] : (i < 2048 ? b[i - 1024] : c[i - 2048]);
  o[i] = v;
}

// ---------------- v slice of qkv (stride QS) -> vt (B,H,D,T) bf16 ----------------
__global__ __launch_bounds__(256) void transpose_v_kernel(const u16* __restrict__ v, u16* __restrict__ vt)
{
  __shared__ u16 tile[32][33];
  int tx = threadIdx.x, ty = threadIdx.y;
  int bh = blockIdx.z; int b = bh >> 4, h = bh & 15;
  int t0 = blockIdx.x * 32, d0 = blockIdx.y * 32;
  const u16* src = v + (size_t)b * Tt * QS + h * Dd;
  #pragma unroll
  for (int j = 0; j < 4; j++) tile[ty + j*8][tx] = src[(size_t)(t0 + ty + j*8) * QS + d0 + tx];
  __syncthreads();
  u16* dst = vt + (size_t)bh * Dd * Tt;
  #pragma unroll
  for (int j = 0; j < 4; j++) dst[(size_t)(d0 + ty + j*8) * Tt + t0 + tx] = tile[tx][ty + j*8];
}

// ============ 8-phase 256x256 GEMM v2 -- hoisted addressing (QKV / W1) ============
// Staging: 4 precomputed per-thread pointers, advanced +=64/K-tile; kh*32 folds into
// the instruction immediate. LDS read offsets precomputed as named scalars.
// #pragma unroll 2 + constexpr KT -> cur/nxt literal -> LDS bases constant.
// Waits: vmcnt(4) at end-ph2 (guards this tile's kh1 halves) and end-ph4 (guards
// next tile's kh0 halves). Never drains mid-loop.
template<int EPI, int KT>
__global__ __launch_bounds__(512, 2) void gemm8p_kernel(
    const u16* __restrict__ A, const u16* __restrict__ BT,
    const float* __restrict__ bias, void* __restrict__ out,
    int ldA, int ldOut)
{
  __shared__ alignas(16) u16 AsU[2][2][256 * 32];
  __shared__ alignas(16) u16 BsU[2][2][256 * 32];

  const int tid  = threadIdx.x;
  const int lane = tid & 63, wid = tid >> 6;
  const int l15  = lane & 15, lg = lane >> 4;

  const int gx  = gridDim.x;
  const int lin = blockIdx.x + gx * blockIdx.y;
  const int nwg = gx * gridDim.y;
  const int wl  = (lin & 7) * (nwg >> 3) + (lin >> 3);
  const int rowBase = (wl % gx) * 256, colBase = (wl / gx) * 256;

  const int wr = wid >> 2, wc = wid & 3;

  f32x4 acc[8][4] = {};

  // --- staging pointers (2 granules per half per thread) ---
  const int s0 = tid, s1 = tid + 512;
  const int r0 = s0 >> 2, w0 = (s0 & 3) ^ ((r0 >> 1) & 3);
  const int r1 = s1 >> 2, w1 = (s1 & 3) ^ ((r1 >> 1) & 3);
  const u16* pA0 = A  + (size_t)(rowBase + r0) * ldA + w0 * 8;
  const u16* pA1 = A  + (size_t)(rowBase + r1) * ldA + w1 * 8;
  const u16* pB0 = BT + (size_t)(colBase + r0) * KT  + w0 * 8;
  const u16* pB1 = BT + (size_t)(colBase + r1) * KT  + w1 * 8;
  const u32 d0 = (u32)s0 * 8, d1 = (u32)s1 * 8;   // LDS granule offsets (u16 units)

  // --- LDS read offsets (u16 units), precomputed ---
#define AOFF8(pm, mi) ({ int r_ = wr*128 + (pm)*64 + (mi)*16 + l15; \
                         (u32)(r_*32 + ((lg ^ ((r_>>1)&3)) << 3)); })
#define BOFF8(ni)     ({ int r_ = wc*64 + (ni)*16 + l15; \
                         (u32)(r_*32 + ((lg ^ ((r_>>1)&3)) << 3)); })
  const u32 a00=AOFF8(0,0), a01=AOFF8(0,1), a02=AOFF8(0,2), a03=AOFF8(0,3);
  const u32 a10=AOFF8(1,0), a11=AOFF8(1,1), a12=AOFF8(1,2), a13=AOFF8(1,3);
  const u32 b0 =BOFF8(0),   b1 =BOFF8(1),   b2 =BOFF8(2),   b3 =BOFF8(3);
#undef AOFF8
#undef BOFF8

  auto mfmaQ = [&](int pm, const bf16x8* a, const bf16x8* b){
    __builtin_amdgcn_s_setprio(1);
    #pragma unroll
    for (int mi = 0; mi < 4; mi++)
      #pragma unroll
      for (int ni = 0; ni < 4; ni++)
        acc[pm * 4 + mi][ni] = mfma16(a[mi], b[ni], acc[pm * 4 + mi][ni]);
    __builtin_amdgcn_s_setprio(0);
  };

  // prologue: stage all 4 halves of tile 0 into buf 0 (order H0=A0,H1=B0,H2=A1,H3=B1)
  gl2lds16(pA0,      &AsU[0][0][d0]); gl2lds16(pA1,      &AsU[0][0][d1]);
  gl2lds16(pB0,      &BsU[0][0][d0]); gl2lds16(pB1,      &BsU[0][0][d1]);
  gl2lds16(pA0 + 32, &AsU[0][1][d0]); gl2lds16(pA1 + 32, &AsU[0][1][d1]);
  gl2lds16(pB0 + 32, &BsU[0][1][d0]); gl2lds16(pB1 + 32, &BsU[0][1][d1]);
  pA0 += 64; pA1 += 64; pB0 += 64; pB1 += 64;
  waitvm<4>();
  __builtin_amdgcn_s_barrier();

  constexpr int nt = KT >> 6;
  bf16x8 a[4], b[4];
  #pragma unroll 2
  for (int t = 0; t < nt - 1; ++t){
    const int cur = t & 1, nxt = cur ^ 1;
    // ph1 (pm0, kh0) | stage H0(t+1) = A-kh0
    a[0]=ldlds(&AsU[cur][0][a00]); a[1]=ldlds(&AsU[cur][0][a01]);
    a[2]=ldlds(&AsU[cur][0][a02]); a[3]=ldlds(&AsU[cur][0][a03]);
    b[0]=ldlds(&BsU[cur][0][b0]);  b[1]=ldlds(&BsU[cur][0][b1]);
    b[2]=ldlds(&BsU[cur][0][b2]);  b[3]=ldlds(&BsU[cur][0][b3]);
    gl2lds16(pA0, &AsU[nxt][0][d0]); gl2lds16(pA1, &AsU[nxt][0][d1]);
    __builtin_amdgcn_s_barrier();
    mfmaQ(0, a, b);
    __builtin_amdgcn_s_barrier();
    // ph2 (pm1, kh0) | stage H1(t+1) = B-kh0 | vmcnt(4): H2(t),H3(t) arrived
    a[0]=ldlds(&AsU[cur][0][a10]); a[1]=ldlds(&AsU[cur][0][a11]);
    a[2]=ldlds(&AsU[cur][0][a12]); a[3]=ldlds(&AsU[cur][0][a13]);
    gl2lds16(pB0, &BsU[nxt][0][d0]); gl2lds16(pB1, &BsU[nxt][0][d1]);
    __builtin_amdgcn_s_barrier();
    mfmaQ(1, a, b);
    waitvm<4>();
    __builtin_amdgcn_s_barrier();
    // ph3 (pm0, kh1) | stage H2(t+1) = A-kh1
    a[0]=ldlds(&AsU[cur][1][a00]); a[1]=ldlds(&AsU[cur][1][a01]);
    a[2]=ldlds(&AsU[cur][1][a02]); a[3]=ldlds(&AsU[cur][1][a03]);
    b[0]=ldlds(&BsU[cur][1][b0]);  b[1]=ldlds(&BsU[cur][1][b1]);
    b[2]=ldlds(&BsU[cur][1][b2]);  b[3]=ldlds(&BsU[cur][1][b3]);
    gl2lds16(pA0 + 32, &AsU[nxt][1][d0]); gl2lds16(pA1 + 32, &AsU[nxt][1][d1]);
    __builtin_amdgcn_s_barrier();
    mfmaQ(0, a, b);
    __builtin_amdgcn_s_barrier();
    // ph4 (pm1, kh1) | stage H3(t+1) = B-kh1 | vmcnt(4): H0(t+1),H1(t+1) arrived
    a[0]=ldlds(&AsU[cur][1][a10]); a[1]=ldlds(&AsU[cur][1][a11]);
    a[2]=ldlds(&AsU[cur][1][a12]); a[3]=ldlds(&AsU[cur][1][a13]);
    gl2lds16(pB0 + 32, &BsU[nxt][1][d0]); gl2lds16(pB1 + 32, &BsU[nxt][1][d1]);
    __builtin_amdgcn_s_barrier();
    mfmaQ(1, a, b);
    waitvm<4>();
    __builtin_amdgcn_s_barrier();
    pA0 += 64; pA1 += 64; pB0 += 64; pB1 += 64;
  }
  { // epilogue tile (no staging)
    const int cur = (nt - 1) & 1;
    a[0]=ldlds(&AsU[cur][0][a00]); a[1]=ldlds(&AsU[cur][0][a01]);
    a[2]=ldlds(&AsU[cur][0][a02]); a[3]=ldlds(&AsU[cur][0][a03]);
    b[0]=ldlds(&BsU[cur][0][b0]);  b[1]=ldlds(&BsU[cur][0][b1]);
    b[2]=ldlds(&BsU[cur][0][b2]);  b[3]=ldlds(&BsU[cur][0][b3]);
    __builtin_amdgcn_s_barrier();
    mfmaQ(0, a, b);
    __builtin_amdgcn_s_barrier();
    a[0]=ldlds(&AsU[cur][0][a10]); a[1]=ldlds(&AsU[cur][0][a11]);
    a[2]=ldlds(&AsU[cur][0][a12]); a[3]=ldlds(&AsU[cur][0][a13]);
    __builtin_amdgcn_s_barrier();
    mfmaQ(1, a, b);
    waitvm<0>();
    __builtin_amdgcn_s_barrier();
    a[0]=ldlds(&AsU[cur][1][a00]); a[1]=ldlds(&AsU[cur][1][a01]);
    a[2]=ldlds(&AsU[cur][1][a02]); a[3]=ldlds(&AsU[cur][1][a03]);
    b[0]=ldlds(&BsU[cur][1][b0]);  b[1]=ldlds(&BsU[cur][1][b1]);
    b[2]=ldlds(&BsU[cur][1][b2]);  b[3]=ldlds(&BsU[cur][1][b3]);
    __builtin_amdgcn_s_barrier();
    mfmaQ(0, a, b);
    __builtin_amdgcn_s_barrier();
    a[0]=ldlds(&AsU[cur][1][a10]); a[1]=ldlds(&AsU[cur][1][a11]);
    a[2]=ldlds(&AsU[cur][1][a12]); a[3]=ldlds(&AsU[cur][1][a13]);
    mfmaQ(1, a, b);
  }

  #pragma unroll
  for (int mi = 0; mi < 8; mi++){
    #pragma unroll
    for (int ni = 0; ni < 4; ni++){
      int row = rowBase + wr * 128 + mi * 16 + lg * 4;
      int col = colBase + wc * 64 + ni * 16 + l15;
      float bc = bias[col];
      #pragma unroll
      for (int r = 0; r < 4; r++){
        float val = acc[mi][ni][r] + bc;
        size_t idx = (size_t)(row + r) * ldOut + col;
        if constexpr (EPI == 2) ((u16*)out)[idx] = f2bf(gelu_f(val));
        else                    ((u16*)out)[idx] = f2bf(col < 1024 ? val * QSCALE : val);
      }
    }
  }
}

// ---------------- counted-vmcnt GEMM v2, 64x64 BK=64, hoisted addressing (Wo / W2) --
// EPI 1: f32 out (+bias+residual)
template<int EPI>
__global__ __launch_bounds__(256, 4) void gemmc_kernel(
    const u16* __restrict__ A, const u16* __restrict__ BT,
    const float* __restrict__ bias, const float* __restrict__ resid,
    void* __restrict__ out, int K, int ldA, int ldOut)
{
  __shared__ alignas(16) u16 As[2][64 * 64];
  __shared__ alignas(16) u16 Bs[2][64 * 64];

  const int tid  = threadIdx.x;
  const int lane = tid & 63, wid = tid >> 6;
  const int l15  = lane & 15, lg = lane >> 4;

  const int gx  = gridDim.x;
  const int lin = blockIdx.x + gx * blockIdx.y;
  const int nwg = gx * gridDim.y;
  const int wl  = (lin & 7) * (nwg >> 3) + (lin >> 3);
  const int rowBase = (wl % gx) * 64, colBase = (wl / gx) * 64;

  const int wr = wid >> 1, wc = wid & 1;

  f32x4 acc[2][2] = {};

  // staging: granule s = tid + 256j, row = s>>3, chunk = (s&7)^(row&7)
  const int s0 = tid, s1 = tid + 256;
  const int r0 = s0 >> 3, w0 = (s0 & 7) ^ (r0 & 7);
  const int r1 = s1 >> 3, w1 = (s1 & 7) ^ (r1 & 7);
  const u16* pA0 = A  + (size_t)(rowBase + r0) * ldA + w0 * 8;
  const u16* pA1 = A  + (size_t)(rowBase + r1) * ldA + w1 * 8;
  const u16* pB0 = BT + (size_t)(colBase + r0) * K   + w0 * 8;
  const u16* pB1 = BT + (size_t)(colBase + r1) * K   + w1 * 8;
  const u32 d0 = (u32)s0 * 8, d1 = (u32)s1 * 8;

#define GOFF(rb, mi, kc) ({ int r_ = (rb) + (mi)*16 + l15; \
                            (u32)(r_*64 + ((((kc)*4 + lg) ^ (r_&7)) << 3)); })
  const u32 oa00=GOFF(wr*32,0,0), oa01=GOFF(wr*32,0,1);
  const u32 oa10=GOFF(wr*32,1,0), oa11=GOFF(wr*32,1,1);
  const u32 ob00=GOFF(wc*32,0,0), ob01=GOFF(wc*32,0,1);
  const u32 ob10=GOFF(wc*32,1,0), ob11=GOFF(wc*32,1,1);
#undef GOFF

  // prologue: stage tile 0
  gl2lds16(pA0, &As[0][d0]); gl2lds16(pA1, &As[0][d1]);
  gl2lds16(pB0, &Bs[0][d0]); gl2lds16(pB1, &Bs[0][d1]);
  pA0 += 64; pA1 += 64; pB0 += 64; pB1 += 64;

  const int nt = K >> 6;
  #pragma unroll 2
  for (int t = 0; t < nt - 1; ++t){
    const int cur = t & 1, nxt = cur ^ 1;
    gl2lds16(pA0, &As[nxt][d0]); gl2lds16(pA1, &As[nxt][d1]);
    gl2lds16(pB0, &Bs[nxt][d0]); gl2lds16(pB1, &Bs[nxt][d1]);
    pA0 += 64; pA1 += 64; pB0 += 64; pB1 += 64;
    waitvm<4>();
    __builtin_amdgcn_s_barrier();
    __builtin_amdgcn_sched_barrier(0);

    bf16x8 A0a=ldlds(&As[cur][oa00]), A0b=ldlds(&As[cur][oa01]);
    bf16x8 A1a=ldlds(&As[cur][oa10]), A1b=ldlds(&As[cur][oa11]);
    bf16x8 B0a=ldlds(&Bs[cur][ob00]), B0b=ldlds(&Bs[cur][ob01]);
    bf16x8 B1a=ldlds(&Bs[cur][ob10]), B1b=ldlds(&Bs[cur][ob11]);
    __builtin_amdgcn_s_setprio(1);
    acc[0][0] = mfma16(A0a, B0a, acc[0][0]); acc[0][0] = mfma16(A0b, B0b, acc[0][0]);
    acc[0][1] = mfma16(A0a, B1a, acc[0][1]); acc[0][1] = mfma16(A0b, B1b, acc[0][1]);
    acc[1][0] = mfma16(A1a, B0a, acc[1][0]); acc[1][0] = mfma16(A1b, B0b, acc[1][0]);
    acc[1][1] = mfma16(A1a, B1a, acc[1][1]); acc[1][1] = mfma16(A1b, B1b, acc[1][1]);
    __builtin_amdgcn_s_setprio(0);

    __builtin_amdgcn_sched_barrier(0);
    __builtin_amdgcn_s_barrier();
  }
  { // epilogue tile
    const int cur = (nt - 1) & 1;
    waitvm<0>();
    __builtin_amdgcn_s_barrier();
    bf16x8 A0a=ldlds(&As[cur][oa00]), A0b=ldlds(&As[cur][oa01]);
    bf16x8 A1a=ldlds(&As[cur][oa10]), A1b=ldlds(&As[cur][oa11]);
    bf16x8 B0a=ldlds(&Bs[cur][ob00]), B0b=ldlds(&Bs[cur][ob01]);
    bf16x8 B1a=ldlds(&Bs[cur][ob10]), B1b=ldlds(&Bs[cur][ob11]);
    acc[0][0] = mfma16(A0a, B0a, acc[0][0]); acc[0][0] = mfma16(A0b, B0b, acc[0][0]);
    acc[0][1] = mfma16(A0a, B1a, acc[0][1]); acc[0][1] = mfma16(A0b, B1b, acc[0][1]);
    acc[1][0] = mfma16(A1a, B0a, acc[1][0]); acc[1][0] = mfma16(A1b, B0b, acc[1][0]);
    acc[1][1] = mfma16(A1a, B1a, acc[1][1]); acc[1][1] = mfma16(A1b, B1b, acc[1][1]);
  }

  #pragma unroll
  for (int mi = 0; mi < 2; mi++){
    #pragma unroll
    for (int ni = 0; ni < 2; ni++){
      int row = rowBase + wr * 32 + mi * 16 + lg * 4;
      int col = colBase + wc * 32 + ni * 16 + l15;
      float bc = bias[col];
      #pragma unroll
      for (int r = 0; r < 4; r++){
        float val = acc[mi][ni][r] + bc;
        size_t idx = (size_t)(row + r) * ldOut + col;
        if constexpr (EPI == 1) ((float*)out)[idx] = val + resid[idx];
        else                    ((u16*)out)[idx]   = f2bf(val);
      }
    }
  }
}

// ---------------- Flash attention, swapped 32x32, KV-split x2 ----------------
__global__ __launch_bounds__(256, 4) void attn_kernel(const u16* __restrict__ q, const u16* __restrict__ k,
    const u16* __restrict__ vt, u16* __restrict__ opart, float* __restrict__ ml)
{
  __shared__ alignas(16) u16 Ks[2][64 * 64];
  __shared__ alignas(16) u16 Vs[2][64 * 64];
  int tid  = threadIdx.x;
  int lane = tid & 63, wid = tid >> 6;
  int l31  = lane & 31, hi = lane >> 5;

  int lin = blockIdx.x + 16 * blockIdx.y;
  int wl  = (lin & 7) * 64 + (lin >> 3);
  int qt  = wl & 15, bh = wl >> 4;
  int b = bh >> 4, h = bh & 15;
  int split = blockIdx.z;
  int kt0 = split * (Tt / 2);

  int qglob = qt * 128 + wid * 32 + l31;

  const u16* qp = q + ((size_t)b * Tt + qglob) * QS + h * Dd + hi * 8;
  bf16x8 qf[4];
  #pragma unroll
  for (int s = 0; s < 4; s++) qf[s] = *(const bf16x8*)(qp + s * 16);

  const u16* kbase = k  + (size_t)b * Tt * QS + h * Dd;
  const u16* vbase = vt + (size_t)bh * Dd * Tt;

  f32x16 yacc[2] = {};
  float m2 = -1e30f, lsum = 0.f;

  int g0 = tid, g1 = tid + 256;
  int r0 = g0 >> 3, cb0 = (g0 & 7) ^ (r0 & 7);
  int r1 = g1 >> 3, cb1 = (g1 & 7) ^ (r1 & 7);

  auto stageKV = [&](int buf, int kt){
    gl2lds16(kbase + (size_t)(kt + r0) * QS + cb0 * 8, (u16*)Ks[buf] + wid * 512);
    gl2lds16(kbase + (size_t)(kt + r1) * QS + cb1 * 8, (u16*)Ks[buf] + 2048 + wid * 512);
    gl2lds16(vbase + (size_t)r0 * Tt + kt + cb0 * 8,   (u16*)Vs[buf] + wid * 512);
    gl2lds16(vbase + (size_t)r1 * Tt + kt + cb1 * 8,   (u16*)Vs[buf] + 2048 + wid * 512);
  };

  stageKV(0, kt0);
  int cur = 0;
  for (int kt = kt0; kt < kt0 + Tt / 2; kt += 64) {
    if (kt + 64 < kt0 + Tt / 2) { stageKV(cur ^ 1, kt + 64); waitvm<4>(); }
    else                        { waitvm<0>(); }
    barrier_pin();

    const u16* Ksb = (const u16*)Ks[cur];
    const u16* Vsb = (const u16*)Vs[cur];
    int rx = l31 & 7;

    f32x16 st[2] = {};
    __builtin_amdgcn_s_setprio(1);
    #pragma unroll
    for (int nb = 0; nb < 2; nb++){
      const u16* krow = Ksb + (nb * 32 + l31) * 64;
      #pragma unroll
      for (int s = 0; s < 4; s++){
        bf16x8 kf = *(const bf16x8*)(krow + (((s * 2 + hi) ^ rx) << 3));
        st[nb] = mfma32(kf, qf[s], st[nb]);
      }
    }
    __builtin_amdgcn_s_setprio(0);

    float tm[16];
    #pragma unroll
    for (int i = 0; i < 16; i++) tm[i] = fmaxf(st[0][i], st[1][i]);
    #pragma unroll
    for (int w = 8; w; w >>= 1)
      #pragma unroll
      for (int i = 0; i < w; i++) tm[i] = fmaxf(tm[i], tm[i + w]);
    u32 ma = __builtin_bit_cast(u32, tm[0]), mb = ma;
    plane_swap(ma, mb);
    float mx = fmaxf(__builtin_bit_cast(float, ma), __builtin_bit_cast(float, mb));

    float mnew = fmaxf(m2, mx);
    float alpha = exp2f_fast(m2 - mnew);
    m2 = mnew;

    #pragma unroll
    for (int nb = 0; nb < 2; nb++)
      #pragma unroll
      for (int i = 0; i < 16; i++)
        st[nb][i] = exp2f_fast(st[nb][i] - m2);

    float ts[16];
    #pragma unroll
    for (int i = 0; i < 16; i++) ts[i] = st[0][i] + st[1][i];
    #pragma unroll
    for (int w = 8; w; w >>= 1)
      #pragma unroll
      for (int i = 0; i < w; i++) ts[i] += ts[i + w];
    u32 sa = __builtin_bit_cast(u32, ts[0]), sb = sa;
    plane_swap(sa, sb);
    lsum = lsum * alpha + __builtin_bit_cast(float, sa) + __builtin_bit_cast(float, sb);

    #pragma unroll
    for (int nd = 0; nd < 2; nd++)
      #pragma unroll
      for (int i = 0; i < 16; i++) yacc[nd][i] *= alpha;

    bf16x8 pb[4];
    #pragma unroll
    for (int nb = 0; nb < 2; nb++){
      u32 c[8];
      #pragma unroll
      for (int i = 0; i < 8; i++) c[i] = cvtpk_bf16(st[nb][2 * i], st[nb][2 * i + 1]);
      plane_swap(c[0], c[2]); plane_swap(c[1], c[3]);
      plane_swap(c[4], c[6]); plane_swap(c[5], c[7]);
      u32 f0[4] = {c[0], c[1], c[2], c[3]};
      u32 f1[4] = {c[4], c[5], c[6], c[7]};
      pb[nb * 2 + 0] = *(bf16x8*)f0;
      pb[nb * 2 + 1] = *(bf16x8*)f1;
    }

    __builtin_amdgcn_s_setprio(1);
    #pragma unroll
    for (int nd = 0; nd < 2; nd++){
      const u16* vrow = Vsb + (nd * 32 + l31) * 64;
      #pragma unroll
      for (int ks = 0; ks < 4; ks++){
        bf16x8 vf = *(const bf16x8*)(vrow + (((ks * 2 + hi) ^ rx) << 3));
        yacc[nd] = mfma32(vf, pb[ks], yacc[nd]);
      }
    }
    __builtin_amdgcn_s_setprio(0);

    __builtin_amdgcn_sched_barrier(0);
    barrier_pin();
    cur ^= 1;
  }

  float inv = 1.0f / lsum;
  u16* op = opart + ((size_t)split * (Bb * Tt) + (size_t)b * Tt + qglob) * Cc + h * Dd;
  #pragma unroll
  for (int nd = 0; nd < 2; nd++){
    #pragma unroll
    for (int g = 0; g < 4; g++){
      ushort4 o;
      o.x = f2bf(yacc[nd][g * 4 + 0] * inv);
      o.y = f2bf(yacc[nd][g * 4 + 1] * inv);
      o.z = f2bf(yacc[nd][g * 4 + 2] * inv);
      o.w = f2bf(yacc[nd][g * 4 + 3] * inv);
      *(ushort4*)(op + nd * 32 + g * 8 + hi * 4) = o;
    }
  }
  if (hi == 0){
    float* mlp = ml + (((size_t)split * (Bb * Tt) + (size_t)b * Tt + qglob) * Hh + h) * 2;
    mlp[0] = m2; mlp[1] = lsum;
  }
}

// ---------------- combine 2 KV-splits (convex combination of normalized partials) ----
__global__ __launch_bounds__(256) void combine_kernel(const u16* __restrict__ opart,
    const float* __restrict__ ml, u16* __restrict__ y)
{
  int row = blockIdx.x;
  int d0  = threadIdx.x * 4;
  int h   = d0 >> 6;
  const float* p0 = ml + ((size_t)row * Hh + h) * 2;
  const float* p1 = ml + (((size_t)(Bb * Tt) + row) * Hh + h) * 2;
  float m0 = p0[0], l0 = p0[1], m1 = p1[0], l1 = p1[1];
  float M  = fmaxf(m0, m1);
  float u0 = l0 * exp2f_fast(m0 - M), u1 = l1 * exp2f_fast(m1 - M);
  float inv = 1.0f / (u0 + u1);
  float w0 = u0 * inv, w1 = u1 * inv;
  ushort4 a = *(const ushort4*)(opart + (size_t)row * Cc + d0);
  ushort4 c = *(const ushort4*)(opart + ((size_t)(Bb * Tt) + row) * Cc + d0);
  ushort4 o;
  o.x = f2bf(bf2f(a.x) * w0 + bf2f(c.x) * w1);
  o.y = f2bf(bf2f(a.y) * w0 + bf2f(c.y) * w1);
  o.z = f2bf(bf2f(a.z) * w0 + bf2f(c.z) * w1);
  o.w = f2bf(bf2f(a.w) * w0 + bf2f(c.w) * w1);
  *(ushort4*)(y + (size_t)row * Cc + d0) = o;
}

extern "C" void kernel_launch(void* const* d_in, const int* in_sizes, int n_in,
                              void* d_out, int out_size, void* d_ws, size_t ws_size,
                              hipStream_t stream)
{
  (void)in_sizes; (void)n_in; (void)out_size; (void)ws_size;
  const float* x    = (const float*)d_in[0];
  const float* Wq   = (const float*)d_in[1];
  const float* bq   = (const float*)d_in[2];
  const float* Wk   = (const float*)d_in[3];
  const float* bk   = (const float*)d_in[4];
  const float* Wv   = (const float*)d_in[5];
  const float* bv   = (const float*)d_in[6];
  const float* Wo   = (const float*)d_in[7];
  const float* bo   = (const float*)d_in[8];
  const float* ln1g = (const float*)d_in[9];
  const float* ln1b = (const float*)d_in[10];
  const float* ln2g = (const float*)d_in[11];
  const float* ln2b = (const float*)d_in[12];
  const float* W1   = (const float*)d_in[13];
  const float* b1   = (const float*)d_in[14];
  const float* W2   = (const float*)d_in[15];
  const float* b2   = (const float*)d_in[16];

  char* ws = (char*)d_ws;
  const size_t MB = 1024 * 1024;
  u16*   wqkvt = (u16*)(ws + 0 * MB);      // 6 MB  (Wq^T | Wk^T | Wv^T rows)
  u16*   wot   = (u16*)(ws + 6 * MB);      // 2 MB
  u16*   w1t   = (u16*)(ws + 8 * MB);      // 8 MB
  u16*   w2t   = (u16*)(ws + 16 * MB);     // 8 MB
  float* bqkv  = (float*)(ws + 24 * MB);   // 12 KB
  u16*   hbuf  = (u16*)(ws + 25 * MB);     // 8 MB  (h2 overlays after QKV gemm)
  u16*   qkv   = (u16*)(ws + 33 * MB);     // 24 MB (mb overlays 33..65 after attn)
  u16*   vtb   = (u16*)(ws + 57 * MB);     // 8 MB
  u16*   yb    = (u16*)(ws + 65 * MB);     // 8 MB
  u16*   opart = (u16*)(ws + 73 * MB);     // 16 MB (2 splits x 8 MB)
  float* x2    = (float*)(ws + 73 * MB);   // 16 MB (written by Wo gemm, after combine)
  float* mlb   = (float*)(ws + 89 * MB);   // 1 MB
  u16*   h2    = hbuf;
  u16*   mb    = qkv;

  dim3 tb(32, 8);
  transpose4_kernel<<<dim3(32, 32, 4), tb, 0, stream>>>(Wq, Wk, Wv, Wo,
      wqkvt, wqkvt + 1024 * 1024, wqkvt + 2048 * 1024, wot);
  transpose_cast_kernel<<<dim3(128, 32), tb, 0, stream>>>(W1, w1t, 1024, 4096);
  transpose_cast_kernel<<<dim3(32, 128), tb, 0, stream>>>(W2, w2t, 4096, 1024);
  pack3_kernel<<<12, 256, 0, stream>>>(bq, bk, bv, bqkv);

  ln_kernel<<<4096, 256, 0, stream>>>(x, ln1g, ln1b, hbuf);

  // fused QKV (8-phase 256^2 v2; EPI 3: q columns pre-scaled by QSCALE)
  gemm8p_kernel<3, 1024><<<dim3(16, 12), 512, 0, stream>>>(hbuf, wqkvt, bqkv, qkv, 1024, 3072);

  transpose_v_kernel<<<dim3(64, 2, 32), tb, 0, stream>>>(qkv + 2048, vtb);

  // KV-split x2 attention + combine
  attn_kernel<<<dim3(16, 32, 2), 256, 0, stream>>>(qkv, qkv + 1024, vtb, opart, mlb);
  combine_kernel<<<4096, 256, 0, stream>>>(opart, mlb, yb);

  // Wo: [4096,1024] x [1024,1024]^T  (64x64 v2)
  gemmc_kernel<1><<<dim3(64, 16), 256, 0, stream>>>(yb, wot, bo, x, x2, 1024, 1024, 1024);

  ln_kernel<<<4096, 256, 0, stream>>>(x2, ln2g, ln2b, h2);

  // W1: [4096,1024] x [4096,1024]^T (8-phase 256^2 v2, gelu)
  gemm8p_kernel<2, 1024><<<dim3(16, 16), 512, 0, stream>>>(h2, w1t, b1, mb, 1024, 4096);

  // W2: [4096,4096] x [1024,4096]^T  (64x64 v2)
  gemmc_kernel<1><<<dim3(64, 16), 256, 0, stream>>>(mb, w2t, b2, x2, (float*)d_out, 4096, 4096, 1024);
}